// Round 1
// baseline (2685.026 us; speedup 1.0000x reference)
//
#include <hip/hip_runtime.h>

#define TOKENS 4096
#define HD 2048
#define FF 8192
#define NE 8
#define NS 2

typedef __attribute__((ext_vector_type(8))) short bf16x8;
typedef __attribute__((ext_vector_type(4))) float f32x4;

__device__ __forceinline__ unsigned rnd_bf(unsigned u) {
  return u + 0x7fffu + ((u >> 16) & 1u);
}
__device__ __forceinline__ unsigned short f2bf(float f) {
  unsigned u = __builtin_bit_cast(unsigned, f);
  return (unsigned short)(rnd_bf(u) >> 16);
}
// pack bf16(lo) into low16, bf16(hi) into high16, via v_perm
__device__ __forceinline__ unsigned pack2bf(float lo, float hi) {
  unsigned ul = rnd_bf(__builtin_bit_cast(unsigned, lo));
  unsigned uh = rnd_bf(__builtin_bit_cast(unsigned, hi));
  return __builtin_amdgcn_perm(uh, ul, 0x07060302u);
}

// ---------------- cast x f32 -> bf16 ----------------
__global__ void cast_x_kernel(const float* __restrict__ x, unsigned short* __restrict__ xb) {
  const size_t i = ((size_t)blockIdx.x * 256 + threadIdx.x) * 4;
  float4 v = *(const float4*)(x + i);
  ushort4 o;
  o.x = f2bf(v.x); o.y = f2bf(v.y); o.z = f2bf(v.z); o.w = f2bf(v.w);
  *(ushort4*)(xb + i) = o;
}

// ---------------- router: logits, softmax, top2, counts ----------------
__global__ void router_kernel(const float* __restrict__ x, const float* __restrict__ wg,
                              float* __restrict__ logits_out, int* __restrict__ topi,
                              float* __restrict__ topv, int* __restrict__ counts) {
  const int wave = threadIdx.x >> 6, lane = threadIdx.x & 63;
  const int t = blockIdx.x * 4 + wave;
  const float* xr = x + (size_t)t * HD;
  float acc[8];
#pragma unroll
  for (int e = 0; e < 8; ++e) acc[e] = 0.f;
  for (int d = lane; d < HD; d += 64) {
    const float xv = xr[d];
    const float4 w0 = *(const float4*)(wg + (size_t)d * 8);
    const float4 w1 = *(const float4*)(wg + (size_t)d * 8 + 4);
    acc[0] += xv * w0.x; acc[1] += xv * w0.y; acc[2] += xv * w0.z; acc[3] += xv * w0.w;
    acc[4] += xv * w1.x; acc[5] += xv * w1.y; acc[6] += xv * w1.z; acc[7] += xv * w1.w;
  }
#pragma unroll
  for (int e = 0; e < 8; ++e) {
#pragma unroll
    for (int off = 32; off > 0; off >>= 1) acc[e] += __shfl_xor(acc[e], off);
  }
  if (lane == 0) {
    *(float4*)(logits_out + (size_t)t * 8)     = make_float4(acc[0], acc[1], acc[2], acc[3]);
    *(float4*)(logits_out + (size_t)t * 8 + 4) = make_float4(acc[4], acc[5], acc[6], acc[7]);
    float mx = acc[0];
#pragma unroll
    for (int e = 1; e < 8; ++e) mx = fmaxf(mx, acc[e]);
    float p[8], s = 0.f;
#pragma unroll
    for (int e = 0; e < 8; ++e) { p[e] = expf(acc[e] - mx); s += p[e]; }
    const float inv = 1.f / s;
    int i1 = 0;
#pragma unroll
    for (int e = 1; e < 8; ++e) if (acc[e] > acc[i1]) i1 = e;
    int i2 = (i1 == 0) ? 1 : 0;
#pragma unroll
    for (int e = 0; e < 8; ++e) if (e != i1 && acc[e] > acc[i2]) i2 = e;
    topi[2 * t]     = i1; topv[2 * t]     = p[i1] * inv;
    topi[2 * t + 1] = i2; topv[2 * t + 1] = p[i2] * inv;
    atomicAdd(&counts[i1], 1);
    atomicAdd(&counts[i2], 1);
  }
}

// ---------------- prefix offsets ----------------
__global__ void offs_kernel(const int* __restrict__ counts, int* __restrict__ offs,
                            int* __restrict__ cursors) {
  if (threadIdx.x == 0) {
    int r = 0;
    for (int e = 0; e < NE; ++e) { offs[e] = r; cursors[e] = r; r += counts[e]; }
  }
}

// ---------------- gather rows into per-expert compact regions ----------------
__global__ void gather_kernel(const unsigned short* __restrict__ xb,
                              const int* __restrict__ topi, const float* __restrict__ topv,
                              int* __restrict__ cursors, unsigned short* __restrict__ xg,
                              int* __restrict__ row_token, float* __restrict__ row_gate) {
  const int wave = threadIdx.x >> 6, lane = threadIdx.x & 63;
  const int t = blockIdx.x * 4 + wave;
  const uint4* src = (const uint4*)(xb + (size_t)t * HD);  // 256 x 16B
#pragma unroll
  for (int j = 0; j < 2; ++j) {
    const int e = topi[2 * t + j];
    int pos = 0;
    if (lane == 0) {
      pos = atomicAdd(&cursors[e], 1);
      row_token[pos] = t;
      row_gate[pos] = topv[2 * t + j];
    }
    pos = __shfl(pos, 0);
    uint4* dst = (uint4*)(xg + (size_t)pos * HD);
#pragma unroll
    for (int c = lane; c < 256; c += 64) dst[c] = src[c];
  }
}

// ---------------- grouped GEMM ----------------
// MODE 0: h = relu(A[MxK=2048] * W1[2048xFF] + b1) -> bf16 hbuf
// MODE 1: out[token] += gate * (A(h)[Mx8192] * W2[8192xHD] + b2)   (atomic f32)
template <int MODE>
__global__ __launch_bounds__(256) void moe_gemm(
    const unsigned short* __restrict__ xb, const unsigned short* __restrict__ xg,
    const unsigned short* __restrict__ hbuf,
    const float* __restrict__ wE, const float* __restrict__ bE,
    const float* __restrict__ wS, const float* __restrict__ bS,
    unsigned short* __restrict__ hout, float* __restrict__ out,
    const int* __restrict__ counts, const int* __restrict__ offs,
    const int* __restrict__ row_token, const float* __restrict__ row_gate) {
  constexpr int K   = (MODE == 0) ? HD : FF;
  constexpr int LDA = K;
  constexpr int LDB = (MODE == 0) ? FF : HD;

  const int e = blockIdx.z;
  int M;
  const unsigned short* A;
  const float* B;
  const float* bias;
  int hbase = 0;
  const int* tok = nullptr;
  const float* gt = nullptr;

  if (e < NE) {
    M = counts[e];
    const int off = offs[e];
    if (MODE == 0) {
      A = xg + (size_t)off * HD;
    } else {
      A = hbuf + (size_t)off * FF;
      tok = row_token + off;
      gt = row_gate + off;
    }
    B = wE + (size_t)e * K * LDB;
    bias = bE + (size_t)e * LDB;
    hbase = off;
  } else {
    M = TOKENS;
    const int se = e - NE;
    hbase = 2 * TOKENS + se * TOKENS;
    if (MODE == 0) A = xb;
    else           A = hbuf + (size_t)hbase * FF;
    B = wS + (size_t)se * K * LDB;
    bias = bS + (size_t)se * LDB;
  }

  const int m0 = blockIdx.y * 128;
  if (m0 >= M) return;
  const int n0 = blockIdx.x * 128;

  __shared__ __align__(16) unsigned short As[128 * 64];
  __shared__ __align__(16) unsigned short Bs[128 * 64];

  const int tid = threadIdx.x;
  const int wave = tid >> 6;
  const int lane = tid & 63;
  const int fr = lane & 15;
  const int fq = lane >> 4;
  const int wr = (wave >> 1) * 64;
  const int wc = (wave & 1) * 64;

  f32x4 acc[4][4];
#pragma unroll
  for (int i = 0; i < 4; ++i)
#pragma unroll
    for (int j = 0; j < 4; ++j) acc[i][j] = (f32x4){0.f, 0.f, 0.f, 0.f};

  // A staging mapping: 128 rows x 8 chunks(16B); 4 per thread
  const int arw = tid >> 3;   // 0..31
  const int ach = tid & 7;
  // B staging mapping: id = tq*256+tid ; n = id&127, kq = id>>7
  const int nB = tid & 127;
  const int kqB = tid >> 7;   // 0..1
  const float* b_src = B + (size_t)(kqB * 4) * LDB + (n0 + nB);
  unsigned short* bs_dst0 = Bs + nB * 64;
  const int bswz = (nB & 7) << 3;

  const int nkt = K / 64;
  for (int kt = 0; kt < nkt; ++kt) {
    // ---- stage A (bf16 -> LDS, XOR-swizzled) ----
#pragma unroll
    for (int i = 0; i < 4; ++i) {
      const int row = i * 32 + arw;
      const uint4 v = *(const uint4*)(A + (size_t)(m0 + row) * LDA + kt * 64 + ach * 8);
      *(uint4*)(As + row * 64 + ((ach * 8) ^ ((row & 7) << 3))) = v;
    }
    // ---- stage B (f32 -> bf16 -> LDS[n][k], XOR-swizzled) ----
#pragma unroll
    for (int tq = 0; tq < 8; ++tq) {
      const int kq = tq * 2 + kqB;  // 0..15
      const float* bp = b_src + ((size_t)kt * 64 + tq * 8) * LDB;
      const float f0 = bp[0];
      const float f1 = bp[LDB];
      const float f2 = bp[2 * LDB];
      const float f3 = bp[3 * LDB];
      uint2 uu;
      uu.x = pack2bf(f0, f1);
      uu.y = pack2bf(f2, f3);
      *(uint2*)(bs_dst0 + ((kq * 4) ^ bswz)) = uu;
    }
    __syncthreads();
    // ---- compute ----
#pragma unroll
    for (int kk = 0; kk < 2; ++kk) {
      bf16x8 af[4], bfr[4];
#pragma unroll
      for (int mi = 0; mi < 4; ++mi) {
        const int row = wr + mi * 16 + fr;
        const int kb = (kk * 32 + fq * 8) ^ ((row & 7) << 3);
        af[mi] = *(const bf16x8*)(As + row * 64 + kb);
      }
#pragma unroll
      for (int ni = 0; ni < 4; ++ni) {
        const int col = wc + ni * 16 + fr;
        const int kb = (kk * 32 + fq * 8) ^ ((col & 7) << 3);
        bfr[ni] = *(const bf16x8*)(Bs + col * 64 + kb);
      }
#pragma unroll
      for (int mi = 0; mi < 4; ++mi)
#pragma unroll
        for (int ni = 0; ni < 4; ++ni)
          acc[mi][ni] = __builtin_amdgcn_mfma_f32_16x16x32_bf16(af[mi], bfr[ni], acc[mi][ni], 0, 0, 0);
    }
    __syncthreads();
  }

  // ---- epilogue ----
  if (MODE == 0) {
#pragma unroll
    for (int ni = 0; ni < 4; ++ni) {
      const int col = n0 + wc + ni * 16 + fr;
      const float bb = bias[col];
#pragma unroll
      for (int mi = 0; mi < 4; ++mi) {
#pragma unroll
        for (int j = 0; j < 4; ++j) {
          const int r = m0 + wr + mi * 16 + fq * 4 + j;
          if (r < M) {
            float v = acc[mi][ni][j] + bb;
            v = v > 0.f ? v : 0.f;
            hout[(size_t)(hbase + r) * FF + col] = f2bf(v);
          }
        }
      }
    }
  } else {
#pragma unroll
    for (int mi = 0; mi < 4; ++mi) {
#pragma unroll
      for (int j = 0; j < 4; ++j) {
        const int r = m0 + wr + mi * 16 + fq * 4 + j;
        if (r < M) {
          const int t = tok ? tok[r] : r;
          const float g = gt ? gt[r] : 1.f;
          float* orow = out + (size_t)t * HD + n0;
#pragma unroll
          for (int ni = 0; ni < 4; ++ni) {
            const int col = wc + ni * 16 + fr;
            atomicAdd(orow + col, g * (acc[mi][ni][j] + bias[n0 + col]));
          }
        }
      }
    }
  }
}

extern "C" void kernel_launch(void* const* d_in, const int* in_sizes, int n_in,
                              void* d_out, int out_size, void* d_ws, size_t ws_size,
                              hipStream_t stream) {
  const float* x     = (const float*)d_in[0];
  const float* ws_w1 = (const float*)d_in[1];
  const float* ws_b1 = (const float*)d_in[2];
  const float* ws_w2 = (const float*)d_in[3];
  const float* ws_b2 = (const float*)d_in[4];
  const float* we_w1 = (const float*)d_in[5];
  const float* we_b1 = (const float*)d_in[6];
  const float* we_w2 = (const float*)d_in[7];
  const float* we_b2 = (const float*)d_in[8];
  const float* wg    = (const float*)d_in[9];

  float* out = (float*)d_out;                       // [4096][2048]
  float* logits = out + (size_t)TOKENS * HD;        // [4096][8]

  char* ws = (char*)d_ws;
  unsigned short* xb   = (unsigned short*)ws;                    // 4096*2048 bf16
  unsigned short* xg   = (unsigned short*)(ws + 16777216);       // (8192+128)*2048 bf16
  unsigned short* hbuf = (unsigned short*)(ws + 50855936);       // (16384+128)*8192 bf16
  char* ctrl = ws + 321388544;
  int*   row_token = (int*)(ctrl);
  float* row_gate  = (float*)(ctrl + 32768);
  int*   topi      = (int*)(ctrl + 65536);
  float* topv      = (float*)(ctrl + 98304);
  int*   counts    = (int*)(ctrl + 131072);
  int*   offs      = (int*)(ctrl + 131104);
  int*   cursors   = (int*)(ctrl + 131136);

  hipMemsetAsync(out, 0, (size_t)TOKENS * HD * sizeof(float), stream);
  hipMemsetAsync(counts, 0, NE * sizeof(int), stream);

  cast_x_kernel<<<8192, 256, 0, stream>>>(x, xb);
  router_kernel<<<1024, 256, 0, stream>>>(x, wg, logits, topi, topv, counts);
  offs_kernel<<<1, 64, 0, stream>>>(counts, offs, cursors);
  gather_kernel<<<1024, 256, 0, stream>>>(xb, topi, topv, cursors, xg, row_token, row_gate);

  // GEMM1: h = relu(x*W1+b1)  grid: N=8192/128=64, M up to 4096/128=32, 10 experts
  moe_gemm<0><<<dim3(64, 32, 10), 256, 0, stream>>>(
      xb, xg, nullptr, we_w1, we_b1, ws_w1, ws_b1, hbuf, nullptr,
      counts, offs, nullptr, nullptr);

  // GEMM2: out += gate*(h*W2+b2)  grid: N=2048/128=16
  moe_gemm<1><<<dim3(16, 32, 10), 256, 0, stream>>>(
      nullptr, nullptr, hbuf, we_w2, we_b2, ws_w2, ws_b2, nullptr, out,
      counts, offs, row_token, row_gate);

  (void)in_sizes; (void)n_in; (void)out_size; (void)ws_size;
}

// Round 2
// 2157.606 us; speedup vs baseline: 1.2444x; 1.2444x over previous
//
#include <hip/hip_runtime.h>

#define TOKENS 4096
#define HD 2048
#define FF 8192
#define NE 8
#define NS 2

typedef __attribute__((ext_vector_type(8))) short bf16x8;
typedef __attribute__((ext_vector_type(4))) float f32x4;

__device__ __forceinline__ unsigned rnd_bf(unsigned u) {
  return u + 0x7fffu + ((u >> 16) & 1u);
}
__device__ __forceinline__ unsigned short f2bf(float f) {
  unsigned u = __builtin_bit_cast(unsigned, f);
  return (unsigned short)(rnd_bf(u) >> 16);
}
__device__ __forceinline__ unsigned pack2bf(float lo, float hi) {
  unsigned ul = rnd_bf(__builtin_bit_cast(unsigned, lo));
  unsigned uh = rnd_bf(__builtin_bit_cast(unsigned, hi));
  return __builtin_amdgcn_perm(uh, ul, 0x07060302u);
}

#define GLDS16(gp, lp)                                                         \
  __builtin_amdgcn_global_load_lds(                                            \
      (const __attribute__((address_space(1))) unsigned*)(const void*)(gp),    \
      (__attribute__((address_space(3))) unsigned*)(lp), 16, 0, 0)

// ---------------- cast x f32 -> bf16 ----------------
__global__ void cast_x_kernel(const float* __restrict__ x, unsigned short* __restrict__ xb) {
  const size_t i = ((size_t)blockIdx.x * 256 + threadIdx.x) * 4;
  float4 v = *(const float4*)(x + i);
  ushort4 o;
  o.x = f2bf(v.x); o.y = f2bf(v.y); o.z = f2bf(v.z); o.w = f2bf(v.w);
  *(ushort4*)(xb + i) = o;
}

// ---------------- router ----------------
__global__ void router_kernel(const float* __restrict__ x, const float* __restrict__ wg,
                              float* __restrict__ logits_out, int* __restrict__ topi,
                              float* __restrict__ topv, int* __restrict__ counts) {
  const int wave = threadIdx.x >> 6, lane = threadIdx.x & 63;
  const int t = blockIdx.x * 4 + wave;
  const float* xr = x + (size_t)t * HD;
  float acc[8];
#pragma unroll
  for (int e = 0; e < 8; ++e) acc[e] = 0.f;
  for (int d = lane; d < HD; d += 64) {
    const float xv = xr[d];
    const float4 w0 = *(const float4*)(wg + (size_t)d * 8);
    const float4 w1 = *(const float4*)(wg + (size_t)d * 8 + 4);
    acc[0] += xv * w0.x; acc[1] += xv * w0.y; acc[2] += xv * w0.z; acc[3] += xv * w0.w;
    acc[4] += xv * w1.x; acc[5] += xv * w1.y; acc[6] += xv * w1.z; acc[7] += xv * w1.w;
  }
#pragma unroll
  for (int e = 0; e < 8; ++e) {
#pragma unroll
    for (int off = 32; off > 0; off >>= 1) acc[e] += __shfl_xor(acc[e], off);
  }
  if (lane == 0) {
    *(float4*)(logits_out + (size_t)t * 8)     = make_float4(acc[0], acc[1], acc[2], acc[3]);
    *(float4*)(logits_out + (size_t)t * 8 + 4) = make_float4(acc[4], acc[5], acc[6], acc[7]);
    float mx = acc[0];
#pragma unroll
    for (int e = 1; e < 8; ++e) mx = fmaxf(mx, acc[e]);
    float p[8], s = 0.f;
#pragma unroll
    for (int e = 0; e < 8; ++e) { p[e] = expf(acc[e] - mx); s += p[e]; }
    const float inv = 1.f / s;
    int i1 = 0;
#pragma unroll
    for (int e = 1; e < 8; ++e) if (acc[e] > acc[i1]) i1 = e;
    int i2 = (i1 == 0) ? 1 : 0;
#pragma unroll
    for (int e = 0; e < 8; ++e) if (e != i1 && acc[e] > acc[i2]) i2 = e;
    topi[2 * t]     = i1; topv[2 * t]     = p[i1] * inv;
    topi[2 * t + 1] = i2; topv[2 * t + 1] = p[i2] * inv;
    atomicAdd(&counts[i1], 1);
    atomicAdd(&counts[i2], 1);
  }
}

__global__ void offs_kernel(const int* __restrict__ counts, int* __restrict__ offs,
                            int* __restrict__ cursors) {
  if (threadIdx.x == 0) {
    int r = 0;
    for (int e = 0; e < NE; ++e) { offs[e] = r; cursors[e] = r; r += counts[e]; }
  }
}

__global__ void gather_kernel(const unsigned short* __restrict__ xb,
                              const int* __restrict__ topi, const float* __restrict__ topv,
                              int* __restrict__ cursors, unsigned short* __restrict__ xg,
                              int* __restrict__ row_token, float* __restrict__ row_gate) {
  const int wave = threadIdx.x >> 6, lane = threadIdx.x & 63;
  const int t = blockIdx.x * 4 + wave;
  const uint4* src = (const uint4*)(xb + (size_t)t * HD);
#pragma unroll
  for (int j = 0; j < 2; ++j) {
    const int e = topi[2 * t + j];
    int pos = 0;
    if (lane == 0) {
      pos = atomicAdd(&cursors[e], 1);
      row_token[pos] = t;
      row_gate[pos] = topv[2 * t + j];
    }
    pos = __shfl(pos, 0);
    uint4* dst = (uint4*)(xg + (size_t)pos * HD);
#pragma unroll
    for (int c = lane; c < 256; c += 64) dst[c] = src[c];
  }
}

// ---------------- pack: f32 [K][N] -> bf16 B^T [N][K] ----------------
template <int K, int N>
__global__ __launch_bounds__(256) void pack_wt(const float* __restrict__ we,
                                               const float* __restrict__ ws,
                                               unsigned short* __restrict__ dstw) {
  const int e = blockIdx.z;
  const float* src = (e < NE) ? (we + (size_t)e * K * N) : (ws + (size_t)(e - NE) * K * N);
  unsigned short* dst = dstw + (size_t)e * K * N;
  const int nt = blockIdx.x * 64;
  const int kt = blockIdx.y * 64;
  __shared__ unsigned short t[64][73];
  const int tid = threadIdx.x;
  const int rr = tid >> 4, cc = (tid & 15) * 4;
#pragma unroll
  for (int i = 0; i < 4; ++i) {
    const int k = rr + i * 16;
    float4 v = *(const float4*)(src + (size_t)(kt + k) * N + nt + cc);
    t[k][cc + 0] = f2bf(v.x);
    t[k][cc + 1] = f2bf(v.y);
    t[k][cc + 2] = f2bf(v.z);
    t[k][cc + 3] = f2bf(v.w);
  }
  __syncthreads();
  const int nr = tid >> 2, kc = (tid & 3) * 16;
  unsigned u[8];
#pragma unroll
  for (int j = 0; j < 8; ++j)
    u[j] = (unsigned)t[kc + 2 * j][nr] | ((unsigned)t[kc + 2 * j + 1][nr] << 16);
  unsigned short* dp = dst + (size_t)(nt + nr) * K + kt + kc;
  uint4 v0; v0.x = u[0]; v0.y = u[1]; v0.z = u[2]; v0.w = u[3];
  uint4 v1; v1.x = u[4]; v1.y = u[5]; v1.z = u[6]; v1.w = u[7];
  *(uint4*)dp = v0;
  *(uint4*)(dp + 8) = v1;
}

// ---------------- bf16 B^T grouped GEMM (m97 structure) ----------------
// MODE 0: h = relu(A[M x 2048] * W1t^T + b1) -> bf16 hbuf
// MODE 1: out[token] += gate * (A[M x 8192] * W2t^T + b2)  (atomic f32)
template <int MODE>
__global__ __launch_bounds__(256) void gemm_bt(
    const unsigned short* __restrict__ Ash,   // MODE0: xb, MODE1: hbuf
    const unsigned short* __restrict__ Art,   // MODE0: xg, MODE1: hbuf
    const unsigned short* __restrict__ wt,    // packed B^T [10][N*K]
    const float* __restrict__ bE, const float* __restrict__ bS,
    unsigned short* __restrict__ hout, float* __restrict__ out,
    const int* __restrict__ counts, const int* __restrict__ offs,
    const int* __restrict__ row_token, const float* __restrict__ row_gate) {
  constexpr int K = (MODE == 0) ? HD : FF;
  constexpr int N = (MODE == 0) ? FF : HD;

  const int e = blockIdx.z;
  int M;
  const unsigned short* A;
  const float* bias;
  int hbase = 0;
  const int* tok = nullptr;
  const float* gt = nullptr;

  if (e < NE) {
    M = counts[e];
    const int off = offs[e];
    if (MODE == 0) A = Art + (size_t)off * K;
    else { A = Art + (size_t)off * K; tok = row_token + off; gt = row_gate + off; }
    bias = bE + (size_t)e * N;
    hbase = off;
  } else {
    M = TOKENS;
    const int se = e - NE;
    hbase = 2 * TOKENS + se * TOKENS;
    if (MODE == 0) A = Ash;
    else           A = Ash + (size_t)hbase * K;
    bias = bS + (size_t)se * N;
  }
  const unsigned short* Bt = wt + (size_t)e * HD * FF;  // [N][K]

  const int m0 = blockIdx.y * 128;
  if (m0 >= M) return;
  const int n0 = blockIdx.x * 128;

  __shared__ __align__(16) unsigned short As[128 * 64];
  __shared__ __align__(16) unsigned short Bs[128 * 64];

  const int tid = threadIdx.x;
  const int wv = tid >> 6;
  const int ln = tid & 63;
  const int fr = ln & 15;
  const int fq = ln >> 4;
  const int wr = (wv >> 1) * 64;
  const int wc = (wv & 1) * 64;
  const int lrow = ln >> 3;        // 0..7
  const int lcol = (ln & 7) * 8;   // ushorts

  f32x4 acc[4][4];
#pragma unroll
  for (int i = 0; i < 4; ++i)
#pragma unroll
    for (int j = 0; j < 4; ++j) acc[i][j] = (f32x4){0.f, 0.f, 0.f, 0.f};

  const unsigned short* a_base = A + (size_t)(m0 + wv * 32 + lrow) * K + lcol;
  const unsigned short* b_base = Bt + (size_t)(n0 + wv * 32 + lrow) * K + lcol;
  unsigned short* as_base = As + (wv * 32) * 64;
  unsigned short* bs_base = Bs + (wv * 32) * 64;

  const int nkt = K / 64;
  for (int kt = 0; kt < nkt; ++kt) {
    const int ko = kt * 64;
#pragma unroll
    for (int i = 0; i < 4; ++i)
      GLDS16(a_base + (size_t)(i * 8) * K + ko, as_base + (i * 8) * 64);
#pragma unroll
    for (int i = 0; i < 4; ++i)
      GLDS16(b_base + (size_t)(i * 8) * K + ko, bs_base + (i * 8) * 64);
    __syncthreads();
#pragma unroll
    for (int kk = 0; kk < 2; ++kk) {
      bf16x8 af[4], bfr[4];
#pragma unroll
      for (int mi = 0; mi < 4; ++mi)
        af[mi] = *(const bf16x8*)(As + (wr + mi * 16 + fr) * 64 + kk * 32 + fq * 8);
#pragma unroll
      for (int ni = 0; ni < 4; ++ni)
        bfr[ni] = *(const bf16x8*)(Bs + (wc + ni * 16 + fr) * 64 + kk * 32 + fq * 8);
#pragma unroll
      for (int mi = 0; mi < 4; ++mi)
#pragma unroll
        for (int ni = 0; ni < 4; ++ni)
          acc[mi][ni] = __builtin_amdgcn_mfma_f32_16x16x32_bf16(af[mi], bfr[ni], acc[mi][ni], 0, 0, 0);
    }
    __syncthreads();
  }

  if (MODE == 0) {
#pragma unroll
    for (int ni = 0; ni < 4; ++ni) {
      const int col = n0 + wc + ni * 16 + fr;
      const float bb = bias[col];
#pragma unroll
      for (int mi = 0; mi < 4; ++mi) {
#pragma unroll
        for (int j = 0; j < 4; ++j) {
          const int r = m0 + wr + mi * 16 + fq * 4 + j;
          if (r < M) {
            float v = acc[mi][ni][j] + bb;
            v = v > 0.f ? v : 0.f;
            hout[(size_t)(hbase + r) * FF + col] = f2bf(v);
          }
        }
      }
    }
  } else {
#pragma unroll
    for (int mi = 0; mi < 4; ++mi) {
#pragma unroll
      for (int j = 0; j < 4; ++j) {
        const int r = m0 + wr + mi * 16 + fq * 4 + j;
        if (r < M) {
          const int t = tok ? tok[r] : r;
          const float g = gt ? gt[r] : 1.f;
          float* orow = out + (size_t)t * HD + n0;
#pragma unroll
          for (int ni = 0; ni < 4; ++ni) {
            const int col = wc + ni * 16 + fr;
            atomicAdd(orow + col, g * (acc[mi][ni][j] + bias[n0 + col]));
          }
        }
      }
    }
  }
}

// =======================================================================
// Legacy f32-B GEMM (round-1) — fallback when ws_size is too small for
// the packed-weight path.
// =======================================================================
template <int MODE>
__global__ __launch_bounds__(256) void moe_gemm(
    const unsigned short* __restrict__ xb, const unsigned short* __restrict__ xg,
    const unsigned short* __restrict__ hbuf,
    const float* __restrict__ wE, const float* __restrict__ bE,
    const float* __restrict__ wS, const float* __restrict__ bS,
    unsigned short* __restrict__ hout, float* __restrict__ out,
    const int* __restrict__ counts, const int* __restrict__ offs,
    const int* __restrict__ row_token, const float* __restrict__ row_gate) {
  constexpr int K   = (MODE == 0) ? HD : FF;
  constexpr int LDA = K;
  constexpr int LDB = (MODE == 0) ? FF : HD;

  const int e = blockIdx.z;
  int M;
  const unsigned short* A;
  const float* B;
  const float* bias;
  int hbase = 0;
  const int* tok = nullptr;
  const float* gt = nullptr;

  if (e < NE) {
    M = counts[e];
    const int off = offs[e];
    if (MODE == 0) {
      A = xg + (size_t)off * HD;
    } else {
      A = hbuf + (size_t)off * FF;
      tok = row_token + off;
      gt = row_gate + off;
    }
    B = wE + (size_t)e * K * LDB;
    bias = bE + (size_t)e * LDB;
    hbase = off;
  } else {
    M = TOKENS;
    const int se = e - NE;
    hbase = 2 * TOKENS + se * TOKENS;
    if (MODE == 0) A = xb;
    else           A = hbuf + (size_t)hbase * FF;
    B = wS + (size_t)se * K * LDB;
    bias = bS + (size_t)se * LDB;
  }

  const int m0 = blockIdx.y * 128;
  if (m0 >= M) return;
  const int n0 = blockIdx.x * 128;

  __shared__ __align__(16) unsigned short As[128 * 64];
  __shared__ __align__(16) unsigned short Bs[128 * 64];

  const int tid = threadIdx.x;
  const int wave = tid >> 6;
  const int lane = tid & 63;
  const int fr = lane & 15;
  const int fq = lane >> 4;
  const int wr = (wave >> 1) * 64;
  const int wc = (wave & 1) * 64;

  f32x4 acc[4][4];
#pragma unroll
  for (int i = 0; i < 4; ++i)
#pragma unroll
    for (int j = 0; j < 4; ++j) acc[i][j] = (f32x4){0.f, 0.f, 0.f, 0.f};

  const int arw = tid >> 3;
  const int ach = tid & 7;
  const int nB = tid & 127;
  const int kqB = tid >> 7;
  const float* b_src = B + (size_t)(kqB * 4) * LDB + (n0 + nB);
  unsigned short* bs_dst0 = Bs + nB * 64;
  const int bswz = (nB & 7) << 3;

  const int nkt = K / 64;
  for (int kt = 0; kt < nkt; ++kt) {
#pragma unroll
    for (int i = 0; i < 4; ++i) {
      const int row = i * 32 + arw;
      const uint4 v = *(const uint4*)(A + (size_t)(m0 + row) * LDA + kt * 64 + ach * 8);
      *(uint4*)(As + row * 64 + ((ach * 8) ^ ((row & 7) << 3))) = v;
    }
#pragma unroll
    for (int tq = 0; tq < 8; ++tq) {
      const int kq = tq * 2 + kqB;
      const float* bp = b_src + ((size_t)kt * 64 + tq * 8) * LDB;
      const float f0 = bp[0];
      const float f1 = bp[LDB];
      const float f2 = bp[2 * LDB];
      const float f3 = bp[3 * LDB];
      uint2 uu;
      uu.x = pack2bf(f0, f1);
      uu.y = pack2bf(f2, f3);
      *(uint2*)(bs_dst0 + ((kq * 4) ^ bswz)) = uu;
    }
    __syncthreads();
#pragma unroll
    for (int kk = 0; kk < 2; ++kk) {
      bf16x8 af[4], bfr[4];
#pragma unroll
      for (int mi = 0; mi < 4; ++mi) {
        const int row = wr + mi * 16 + fr;
        const int kb = (kk * 32 + fq * 8) ^ ((row & 7) << 3);
        af[mi] = *(const bf16x8*)(As + row * 64 + kb);
      }
#pragma unroll
      for (int ni = 0; ni < 4; ++ni) {
        const int col = wc + ni * 16 + fr;
        const int kb = (kk * 32 + fq * 8) ^ ((col & 7) << 3);
        bfr[ni] = *(const bf16x8*)(Bs + col * 64 + kb);
      }
#pragma unroll
      for (int mi = 0; mi < 4; ++mi)
#pragma unroll
        for (int ni = 0; ni < 4; ++ni)
          acc[mi][ni] = __builtin_amdgcn_mfma_f32_16x16x32_bf16(af[mi], bfr[ni], acc[mi][ni], 0, 0, 0);
    }
    __syncthreads();
  }

  if (MODE == 0) {
#pragma unroll
    for (int ni = 0; ni < 4; ++ni) {
      const int col = n0 + wc + ni * 16 + fr;
      const float bb = bias[col];
#pragma unroll
      for (int mi = 0; mi < 4; ++mi) {
#pragma unroll
        for (int j = 0; j < 4; ++j) {
          const int r = m0 + wr + mi * 16 + fq * 4 + j;
          if (r < M) {
            float v = acc[mi][ni][j] + bb;
            v = v > 0.f ? v : 0.f;
            hout[(size_t)(hbase + r) * FF + col] = f2bf(v);
          }
        }
      }
    }
  } else {
#pragma unroll
    for (int mi = 0; mi < 4; ++mi) {
#pragma unroll
      for (int j = 0; j < 4; ++j) {
        const int r = m0 + wr + mi * 16 + fq * 4 + j;
        if (r < M) {
          const int t = tok ? tok[r] : r;
          const float g = gt ? gt[r] : 1.f;
          float* orow = out + (size_t)t * HD + n0;
#pragma unroll
          for (int ni = 0; ni < 4; ++ni) {
            const int col = wc + ni * 16 + fr;
            atomicAdd(orow + col, g * (acc[mi][ni][j] + bias[n0 + col]));
          }
        }
      }
    }
  }
}

extern "C" void kernel_launch(void* const* d_in, const int* in_sizes, int n_in,
                              void* d_out, int out_size, void* d_ws, size_t ws_size,
                              hipStream_t stream) {
  const float* x     = (const float*)d_in[0];
  const float* ws_w1 = (const float*)d_in[1];
  const float* ws_b1 = (const float*)d_in[2];
  const float* ws_w2 = (const float*)d_in[3];
  const float* ws_b2 = (const float*)d_in[4];
  const float* we_w1 = (const float*)d_in[5];
  const float* we_b1 = (const float*)d_in[6];
  const float* we_w2 = (const float*)d_in[7];
  const float* we_b2 = (const float*)d_in[8];
  const float* wg    = (const float*)d_in[9];

  float* out = (float*)d_out;
  float* logits = out + (size_t)TOKENS * HD;

  const size_t NEED = 655097856;  // wt 335.5M + hbuf 268.4M + xb 16.8M + xg 34.1M + ctrl

  hipMemsetAsync(out, 0, (size_t)TOKENS * HD * sizeof(float), stream);

  if (ws_size >= NEED) {
    // ---------- packed bf16 path ----------
    char* ws = (char*)d_ws;
    unsigned short* wt   = (unsigned short*)ws;                   // 335,544,320 B (W1t then W2t)
    unsigned short* hbuf = (unsigned short*)(ws + 335544320);     // 268,435,456 B
    unsigned short* xb   = (unsigned short*)(ws + 603979776);     // 16,777,216 B
    unsigned short* xg   = (unsigned short*)(ws + 620756992);     // 34,078,720 B
    char* ctrl = ws + 654835712;
    int*   row_token = (int*)(ctrl);
    float* row_gate  = (float*)(ctrl + 32768);
    int*   topi      = (int*)(ctrl + 65536);
    float* topv      = (float*)(ctrl + 98304);
    int*   counts    = (int*)(ctrl + 131072);
    int*   offs      = (int*)(ctrl + 131104);
    int*   cursors   = (int*)(ctrl + 131136);

    hipMemsetAsync(counts, 0, NE * sizeof(int), stream);
    cast_x_kernel<<<8192, 256, 0, stream>>>(x, xb);
    router_kernel<<<1024, 256, 0, stream>>>(x, wg, logits, topi, topv, counts);
    offs_kernel<<<1, 64, 0, stream>>>(counts, offs, cursors);
    gather_kernel<<<1024, 256, 0, stream>>>(xb, topi, topv, cursors, xg, row_token, row_gate);

    // pack W1 [10][2048][8192] f32 -> [10][8192][2048] bf16
    pack_wt<HD, FF><<<dim3(FF / 64, HD / 64, 10), 256, 0, stream>>>(we_w1, ws_w1, wt);
    // GEMM1: h = relu(x*W1+b1)
    gemm_bt<0><<<dim3(64, 32, 10), 256, 0, stream>>>(
        xb, xg, wt, we_b1, ws_b1, hbuf, nullptr, counts, offs, nullptr, nullptr);
    // pack W2 [10][8192][2048] f32 -> [10][2048][8192] bf16 (reuses wt)
    pack_wt<FF, HD><<<dim3(HD / 64, FF / 64, 10), 256, 0, stream>>>(we_w2, ws_w2, wt);
    // GEMM2: out += gate*(h*W2+b2)
    gemm_bt<1><<<dim3(16, 32, 10), 256, 0, stream>>>(
        hbuf, hbuf, wt, we_b2, ws_b2, nullptr, out, counts, offs, row_token, row_gate);
  } else {
    // ---------- fallback: round-1 f32-B path ----------
    char* ws = (char*)d_ws;
    unsigned short* xb   = (unsigned short*)ws;
    unsigned short* xg   = (unsigned short*)(ws + 16777216);
    unsigned short* hbuf = (unsigned short*)(ws + 50855936);
    char* ctrl = ws + 321388544;
    int*   row_token = (int*)(ctrl);
    float* row_gate  = (float*)(ctrl + 32768);
    int*   topi      = (int*)(ctrl + 65536);
    float* topv      = (float*)(ctrl + 98304);
    int*   counts    = (int*)(ctrl + 131072);
    int*   offs      = (int*)(ctrl + 131104);
    int*   cursors   = (int*)(ctrl + 131136);

    hipMemsetAsync(counts, 0, NE * sizeof(int), stream);
    cast_x_kernel<<<8192, 256, 0, stream>>>(x, xb);
    router_kernel<<<1024, 256, 0, stream>>>(x, wg, logits, topi, topv, counts);
    offs_kernel<<<1, 64, 0, stream>>>(counts, offs, cursors);
    gather_kernel<<<1024, 256, 0, stream>>>(xb, topi, topv, cursors, xg, row_token, row_gate);

    moe_gemm<0><<<dim3(64, 32, 10), 256, 0, stream>>>(
        xb, xg, nullptr, we_w1, we_b1, ws_w1, ws_b1, hbuf, nullptr,
        counts, offs, nullptr, nullptr);
    moe_gemm<1><<<dim3(16, 32, 10), 256, 0, stream>>>(
        nullptr, nullptr, hbuf, we_w2, we_b2, ws_w2, ws_b2, nullptr, out,
        counts, offs, row_token, row_gate);
  }

  (void)in_sizes; (void)n_in; (void)out_size; (void)ws_size;
}